// Round 6
// baseline (205.187 us; speedup 1.0000x reference)
//
#include <hip/hip_runtime.h>
#include <hip/hip_cooperative_groups.h>

namespace cg = cooperative_groups;

#define WG 256
#define G64 64                 // num_graphs (fixed by problem)
#define SPLITS 8               // blocks per graph in the acc phase
#define NBLK (G64 * SPLITS)    // 512 blocks, 256 thr = 2 blocks/CU -> co-resident
#define SCALEI 1048576         // 2^20 fixed-point sigmoid quantization
#define ISCALE 9.5367431640625e-07f

// ---------------------------------------------------------------------------
// Single cooperative dispatch (kills 2 launch gaps + the cursor memset):
//  phase 0: zero cursor + out, node_off[g] = lower_bound(batch, g)
//  sync
//  phase 1: (a) counting-sort claim+write of this block's edge chunk into the
//           per-graph bucket (block-aggregated cursor atomics); (b) OVERLAPPED
//           node-item accumulation for this block's (g,split) node range into
//           the LDS integer delta-histogram (independent of the bucket, hides
//           the claim/gather latency under VALU work).
//  sync
//  phase 2: edge items of graph g from the contiguous bucket; prefix; flush.
// Delta-histogram (proven R5): per item 3 native ds_add_u32 deltas
// {q0, q1-q0, 2^20-q1} at clamp(ib..ib+2, 0, 33); telescopes exactly, so
// saturation is exact. NEVER float LDS atomics (CAS loop, 7x serialization).
// Per-block mass <= ~300 items * 2^20 ~ 3e8 << 2^31: no overflow.
// ---------------------------------------------------------------------------
__global__ __launch_bounds__(WG) void k_fused(const float* __restrict__ x,
                                              const float* __restrict__ v,
                                              const float* __restrict__ lin,
                                              const int* __restrict__ edge,
                                              const int* __restrict__ batch,
                                              int2* __restrict__ bucket,
                                              int* __restrict__ cursor,
                                              int* __restrict__ node_off,
                                              float* __restrict__ out,
                                              int E, int N, int CAP) {
    __shared__ int   hist[34 * 32];   // [delta-slot 0..33][t], int fixed-point
    __shared__ float colf[32 * 32];   // prefixed float result
    __shared__ int   lc[G64], lb[G64];

    cg::grid_group grid = cg::this_grid();
    int tid = threadIdx.x;
    int bid = blockIdx.x;
    int flat = bid * WG + tid;

    // ---- phase 0: zeroing + node_off ----
    for (int i = tid; i < 34 * 32; i += WG) hist[i] = 0;
    if (flat < 16384) ((float4*)out)[flat] = make_float4(0.f, 0.f, 0.f, 0.f);
    if (flat < G64) cursor[flat] = 0;
    if (flat >= 16384 && flat < 16384 + G64 + 1) {
        int val = flat - 16384;
        int lo = 0, hi = N;
        while (lo < hi) {
            int mid = (lo + hi) >> 1;
            if (batch[mid] < val) lo = mid + 1; else hi = mid;
        }
        node_off[val] = lo;
    }
    grid.sync();

    int g = bid / SPLITS, split = bid % SPLITS;
    int t = tid & 31, sub = tid >> 5;
    float v0 = v[t], v1 = v[32 + t], v2 = v[64 + t];
    float lin0 = lin[0];
    float dlin = lin[1] - lin[0];                 // > 0
    const float LOG2E = 1.4426950408889634f;
    float d2 = 200.f * dlin * LOG2E;              // exp-step in log2 units (~20.5)
    float inv_dlin = 1.f / dlin;
    float fstep = exp2f(-d2);                     // e-ratio per threshold (6.8e-7)

    // ---- phase 1a: bucket my edge chunk (flat chunk by bid) ----
    int c0 = (int)((long long)E * bid / NBLK);
    int c1 = (int)((long long)E * (bid + 1) / NBLK);
    for (int ts = c0; ts < c1; ts += WG) {
        if (tid < G64) lc[tid] = 0;
        __syncthreads();
        int i = ts + tid;
        int es = 0, ed = 0, eg = 0, er = 0, has = 0;
        if (i < c1) {
            es = edge[i];
            ed = edge[E + i];
            eg = batch[es];
            er = atomicAdd(&lc[eg], 1);
            has = 1;
        }
        __syncthreads();
        if (tid < G64 && lc[tid]) lb[tid] = atomicAdd(&cursor[tid], lc[tid]);
        __syncthreads();
        if (has) {
            int pos = lb[eg] + er;
            if (pos < CAP) bucket[(size_t)eg * CAP + pos] = make_int2(es, ed);
        }
    }

    // ---- phase 1b: node items (+) for (g, split), overlapped with claims ----
    int n0 = node_off[g], n1 = node_off[g + 1];
    int nn = n1 - n0;
    int a0 = n0 + (int)((long long)nn * split / SPLITS);
    int a1 = n0 + (int)((long long)nn * (split + 1) / SPLITS);
    for (int idx = a0 + sub; idx < a1; idx += 8) {
        const float* xr = x + (size_t)idx * 3;
        float h = xr[0] * v0 + xr[1] * v1 + xr[2] * v2;
        float bs = (h - lin0) * inv_dlin;         // b* where sigmoid = 0.5
        float bF = floorf(bs);
        float e0 = exp2f((bs - bF) * d2);         // in [1, 2^20.5)
        float s0 = __builtin_amdgcn_rcpf(1.f + e0);
        float s1 = __builtin_amdgcn_rcpf(fmaf(e0, fstep, 1.f));
        int q0 = (int)(s0 * (float)SCALEI);
        int q1 = (int)(s1 * (float)SCALEI);
        int ib = (int)bF;
        int i0 = min(33, max(0, ib));
        int i1 = min(33, max(0, ib + 1));
        int i2 = min(33, max(0, ib + 2));
        atomicAdd(&hist[i0 * 32 + t], q0);
        atomicAdd(&hist[i1 * 32 + t], q1 - q0);
        atomicAdd(&hist[i2 * 32 + t], SCALEI - q1);
    }

    grid.sync();

    // ---- phase 2: edge items (-) of graph g from the contiguous bucket ----
    int ne = cursor[g]; if (ne > CAP) ne = CAP;
    int ipc = (ne + SPLITS - 1) / SPLITS;
    int lo = split * ipc;
    int hi = lo + ipc; if (hi > ne) hi = ne;
    for (int k = lo + sub; k < hi; k += 8) {
        int2 sd = bucket[(size_t)g * CAP + k];
        const float* xs = x + (size_t)sd.x * 3;
        const float* xd = x + (size_t)sd.y * 3;
        float hs = xs[0] * v0 + xs[1] * v1 + xs[2] * v2;
        float hd = xd[0] * v0 + xd[1] * v1 + xd[2] * v2;
        float h = fmaxf(hs, hd);
        float bs = (h - lin0) * inv_dlin;
        float bF = floorf(bs);
        float e0 = exp2f((bs - bF) * d2);
        float s0 = __builtin_amdgcn_rcpf(1.f + e0);
        float s1 = __builtin_amdgcn_rcpf(fmaf(e0, fstep, 1.f));
        int q0 = (int)(s0 * (float)SCALEI);
        int q1 = (int)(s1 * (float)SCALEI);
        int ib = (int)bF;
        int i0 = min(33, max(0, ib));
        int i1 = min(33, max(0, ib + 1));
        int i2 = min(33, max(0, ib + 2));
        atomicAdd(&hist[i0 * 32 + t], -q0);
        atomicAdd(&hist[i1 * 32 + t], q0 - q1);
        atomicAdd(&hist[i2 * 32 + t], q1 - SCALEI);
    }

    __syncthreads();
    // prefix over b per t-column (32 distinct banks), scale to float
    if (tid < 32) {
        int run = 0;
#pragma unroll
        for (int b = 0; b < 32; ++b) {
            run += hist[b * 32 + tid];
            colf[b * 32 + tid] = (float)run * ISCALE;
        }
    }
    __syncthreads();
    for (int c = tid; c < 1024; c += WG)
        unsafeAtomicAdd(&out[((size_t)g << 10) + c], colf[c]);
}

extern "C" void kernel_launch(void* const* d_in, const int* in_sizes, int n_in,
                              void* d_out, int out_size, void* d_ws, size_t ws_size,
                              hipStream_t stream) {
    const float* x     = (const float*)d_in[0];
    const float* v     = (const float*)d_in[1];
    const float* lin   = (const float*)d_in[2];
    const int*   edge  = (const int*)d_in[3];
    const int*   batch = (const int*)d_in[4];
    int N = in_sizes[4];
    int E = in_sizes[3] / 2;
    (void)n_in; (void)out_size;

    float* out = (float*)d_out;

    // workspace: [cursor 64][node_off 65][pad to 1024B][bucket G64*CAP*8B]
    int* cursor   = (int*)d_ws;
    int* node_off = cursor + G64;
    int2* bucket  = (int2*)((char*)d_ws + 1024);
    long long cap_ws = (long long)((ws_size - 1024) / ((size_t)G64 * sizeof(int2)));
    int CAP = (int)(cap_ws < (long long)E ? cap_ws : (long long)E);

    void* args[] = {(void*)&x, (void*)&v, (void*)&lin, (void*)&edge, (void*)&batch,
                    (void*)&bucket, (void*)&cursor, (void*)&node_off, (void*)&out,
                    (void*)&E, (void*)&N, (void*)&CAP};
    hipLaunchCooperativeKernel((void*)k_fused, dim3(NBLK), dim3(WG), args, 0, stream);
}

// Round 7
// 87.903 us; speedup vs baseline: 2.3342x; 2.3342x over previous
//
#include <hip/hip_runtime.h>

#define WG 256
#define G64 64       // num_graphs (fixed by problem)
#define SPLITS 16    // blocks per graph in k_acc
#define SCALEI 1048576        // 2^20 fixed-point for sigmoid quantization
#define ISCALE 9.5367431640625e-07f   // 1/2^20

// ---------------------------------------------------------------------------
// k_bucket (proven R3/R5 structure): one thread per edge. g = batch[src];
// block-aggregated cursor bump (64 global atomics per block); stores the int2
// endpoint indices at the claimed slot (x is 600 KB -> L2-resident, k_acc
// gathers coords itself). Blocks 0..63 zero out[g]'s 4 KB slab (replaces the
// memset(out) dispatch). Block 0 computes node_off = lower_bound(batch, g).
// NOTE: do NOT fuse the pipeline with grid.sync() — R6 measured ~50 us per
// grid-wide barrier on MI355X (device-scope sync = cross-XCD L2 flush).
// ---------------------------------------------------------------------------
__global__ __launch_bounds__(WG) void k_bucket(const int* __restrict__ edge,
                                               const int* __restrict__ batch,
                                               int2* __restrict__ bucket,
                                               int* __restrict__ cursor,
                                               int* __restrict__ node_off,
                                               float* __restrict__ out,
                                               int E, int N, int CAP) {
    __shared__ int lc[G64], lb[G64];
    int tid = threadIdx.x;
    int bid = blockIdx.x;
    if (tid < G64) lc[tid] = 0;

    if (bid < G64) {  // zero this graph's output slab (1024 floats)
        float4* o4 = (float4*)(out + ((size_t)bid << 10));
        o4[tid] = make_float4(0.f, 0.f, 0.f, 0.f);
    }
    __syncthreads();

    int e = bid * WG + tid;
    int g = 0, r = 0, s = 0, d = 0;
    if (e < E) {
        s = edge[e];
        d = edge[E + e];
        g = batch[s];
        r = atomicAdd(&lc[g], 1);
    }
    __syncthreads();
    if (tid < G64 && lc[tid]) lb[tid] = atomicAdd(&cursor[tid], lc[tid]);
    __syncthreads();
    if (e < E) {
        int pos = lb[g] + r;
        if (pos < CAP) bucket[(size_t)g * CAP + pos] = make_int2(s, d);
    }

    if (bid == 0 && tid <= G64) {
        int lo = 0, hi = N;
        while (lo < hi) {
            int mid = (lo + hi) >> 1;
            if (batch[mid] < tid) lo = mid + 1; else hi = mid;
        }
        node_off[tid] = lo;
    }
}

// ---------------------------------------------------------------------------
// k_acc: block (g, split). INTEGER delta-histogram in LDS (proven R5).
// Per item 3 native ds_add_u32 deltas {q0, q1-q0, 2^20-q1} at
// clamp(ib..ib+2, 0, 33); telescopes exactly -> saturation exact.
// NEVER float LDS atomics (CAS loop, 7x serialization, R2).
// Edge loop is manually 2x unrolled: bucket loads + all four x-gathers issue
// before either compute, halving the exposed L2 latency chain (the loop is
// latency-bound at 2 blocks/CU, not throughput-bound).
// ---------------------------------------------------------------------------
__global__ __launch_bounds__(WG) void k_acc(const float* __restrict__ x,
                                            const float* __restrict__ v,
                                            const int2* __restrict__ bucket,
                                            const float* __restrict__ lin,
                                            const int* __restrict__ cursor,
                                            const int* __restrict__ node_off,
                                            float* __restrict__ out, int CAP) {
    __shared__ int   hist[34 * 32];   // [delta-slot 0..33][t]
    __shared__ float colf[32 * 32];   // prefixed float result
    int tid = threadIdx.x;
    for (int i = tid; i < 34 * 32; i += WG) hist[i] = 0;

    int g = blockIdx.x;
    int n0 = node_off[g], n1 = node_off[g + 1];
    int nn = n1 - n0;
    int ne = cursor[g]; if (ne > CAP) ne = CAP;
    int L = nn + ne;
    int ipc = (L + SPLITS - 1) / SPLITS;
    int lo = blockIdx.y * ipc;
    int hi = lo + ipc; if (hi > L) hi = L;

    int t = tid & 31, sub = tid >> 5;
    float v0 = v[t], v1 = v[32 + t], v2 = v[64 + t];

    float lin0 = lin[0];
    float dlin = lin[1] - lin[0];                 // > 0
    const float LOG2E = 1.4426950408889634f;
    float d2 = 200.f * dlin * LOG2E;              // exp-step in log2 units (~20.5)
    float inv_dlin = 1.f / dlin;
    float fstep = exp2f(-d2);                     // e-ratio per threshold (6.8e-7)
    __syncthreads();

    // ---- node items (+): heights from contiguous x rows ----
    int nhi = hi < nn ? hi : nn;
    for (int idx = lo + sub; idx < nhi; idx += 8) {
        const float* xr = x + (size_t)(n0 + idx) * 3;
        float h = xr[0] * v0 + xr[1] * v1 + xr[2] * v2;
        float bs = (h - lin0) * inv_dlin;         // b* where sigmoid = 0.5
        float bF = floorf(bs);
        float e0 = exp2f((bs - bF) * d2);         // in [1, 2^20.5)
        float s0 = __builtin_amdgcn_rcpf(1.f + e0);
        float s1 = __builtin_amdgcn_rcpf(fmaf(e0, fstep, 1.f));
        int q0 = (int)(s0 * (float)SCALEI);
        int q1 = (int)(s1 * (float)SCALEI);
        int ib = (int)bF;
        int i0 = min(33, max(0, ib));
        int i1 = min(33, max(0, ib + 1));
        int i2 = min(33, max(0, ib + 2));
        atomicAdd(&hist[i0 * 32 + t], q0);
        atomicAdd(&hist[i1 * 32 + t], q1 - q0);
        atomicAdd(&hist[i2 * 32 + t], SCALEI - q1);
    }

    // ---- edge items (-): 2x unrolled to overlap the L2 gather chains ----
    const int2* bk = bucket + (size_t)g * CAP - nn;   // index by item idx
    int elo = lo > nn ? lo : nn;
    int idx = elo + sub;
    for (; idx + 8 < hi; idx += 16) {
        int2 sdA = bk[idx];
        int2 sdB = bk[idx + 8];
        const float* xsA = x + (size_t)sdA.x * 3;
        const float* xdA = x + (size_t)sdA.y * 3;
        const float* xsB = x + (size_t)sdB.x * 3;
        const float* xdB = x + (size_t)sdB.y * 3;
        float hsA = xsA[0] * v0 + xsA[1] * v1 + xsA[2] * v2;
        float hdA = xdA[0] * v0 + xdA[1] * v1 + xdA[2] * v2;
        float hsB = xsB[0] * v0 + xsB[1] * v1 + xsB[2] * v2;
        float hdB = xdB[0] * v0 + xdB[1] * v1 + xdB[2] * v2;
        float hA = fmaxf(hsA, hdA);
        float hB = fmaxf(hsB, hdB);

        float bsA = (hA - lin0) * inv_dlin;
        float bFA = floorf(bsA);
        float e0A = exp2f((bsA - bFA) * d2);
        float s0A = __builtin_amdgcn_rcpf(1.f + e0A);
        float s1A = __builtin_amdgcn_rcpf(fmaf(e0A, fstep, 1.f));
        int q0A = (int)(s0A * (float)SCALEI);
        int q1A = (int)(s1A * (float)SCALEI);
        int ibA = (int)bFA;
        atomicAdd(&hist[min(33, max(0, ibA)) * 32 + t], -q0A);
        atomicAdd(&hist[min(33, max(0, ibA + 1)) * 32 + t], q0A - q1A);
        atomicAdd(&hist[min(33, max(0, ibA + 2)) * 32 + t], q1A - SCALEI);

        float bsB = (hB - lin0) * inv_dlin;
        float bFB = floorf(bsB);
        float e0B = exp2f((bsB - bFB) * d2);
        float s0B = __builtin_amdgcn_rcpf(1.f + e0B);
        float s1B = __builtin_amdgcn_rcpf(fmaf(e0B, fstep, 1.f));
        int q0B = (int)(s0B * (float)SCALEI);
        int q1B = (int)(s1B * (float)SCALEI);
        int ibB = (int)bFB;
        atomicAdd(&hist[min(33, max(0, ibB)) * 32 + t], -q0B);
        atomicAdd(&hist[min(33, max(0, ibB + 1)) * 32 + t], q0B - q1B);
        atomicAdd(&hist[min(33, max(0, ibB + 2)) * 32 + t], q1B - SCALEI);
    }
    for (; idx < hi; idx += 8) {
        int2 sd = bk[idx];
        const float* xs = x + (size_t)sd.x * 3;
        const float* xd = x + (size_t)sd.y * 3;
        float hs = xs[0] * v0 + xs[1] * v1 + xs[2] * v2;
        float hd = xd[0] * v0 + xd[1] * v1 + xd[2] * v2;
        float h = fmaxf(hs, hd);
        float bs = (h - lin0) * inv_dlin;
        float bF = floorf(bs);
        float e0 = exp2f((bs - bF) * d2);
        float s0 = __builtin_amdgcn_rcpf(1.f + e0);
        float s1 = __builtin_amdgcn_rcpf(fmaf(e0, fstep, 1.f));
        int q0 = (int)(s0 * (float)SCALEI);
        int q1 = (int)(s1 * (float)SCALEI);
        int ib = (int)bF;
        atomicAdd(&hist[min(33, max(0, ib)) * 32 + t], -q0);
        atomicAdd(&hist[min(33, max(0, ib + 1)) * 32 + t], q0 - q1);
        atomicAdd(&hist[min(33, max(0, ib + 2)) * 32 + t], q1 - SCALEI);
    }

    __syncthreads();
    // prefix over b per t-column (banks distinct across the 32 lanes), scale
    if (tid < 32) {
        int run = 0;
#pragma unroll
        for (int b = 0; b < 32; ++b) {
            run += hist[b * 32 + tid];
            colf[b * 32 + tid] = (float)run * ISCALE;
        }
    }
    __syncthreads();
    for (int c = tid; c < 1024; c += WG)
        unsafeAtomicAdd(&out[((size_t)g << 10) + c], colf[c]);
}

extern "C" void kernel_launch(void* const* d_in, const int* in_sizes, int n_in,
                              void* d_out, int out_size, void* d_ws, size_t ws_size,
                              hipStream_t stream) {
    const float* x     = (const float*)d_in[0];
    const float* v     = (const float*)d_in[1];
    const float* lin   = (const float*)d_in[2];
    const int*   edge  = (const int*)d_in[3];
    const int*   batch = (const int*)d_in[4];
    int N = in_sizes[4];
    int E = in_sizes[3] / 2;

    float* out = (float*)d_out;

    // workspace: [cursor 64][node_off 65][pad to 1024B][bucket G64*CAP*8B]
    int* cursor   = (int*)d_ws;
    int* node_off = cursor + G64;
    int2* bucket  = (int2*)((char*)d_ws + 1024);
    long long cap_ws = (long long)((ws_size - 1024) / ((size_t)G64 * sizeof(int2)));
    int CAP = (int)(cap_ws < (long long)E ? cap_ws : (long long)E);

    hipMemsetAsync(cursor, 0, G64 * sizeof(int), stream);

    k_bucket<<<(E + WG - 1) / WG, WG, 0, stream>>>(edge, batch, bucket, cursor,
                                                   node_off, out, E, N, CAP);
    dim3 grid(G64, SPLITS);
    k_acc<<<grid, WG, 0, stream>>>(x, v, bucket, lin, cursor, node_off, out, CAP);
}

// Round 8
// 82.606 us; speedup vs baseline: 2.4839x; 1.0641x over previous
//
#include <hip/hip_runtime.h>

#define WG 256
#define G64 64       // num_graphs (fixed by problem)
#define SPLITS 16    // blocks per graph in k_acc
#define EPT 4        // edges per thread in k_bucket
#define EPB (WG * EPT)
#define SCALEI 1048576        // 2^20 fixed-point for sigmoid quantization
#define ISCALE 9.5367431640625e-07f   // 1/2^20

// ---------------------------------------------------------------------------
// k_bucket: 4 edges per thread (int4 loads), 64 block-aggregated cursor
// atomics per 1024 edges (4x fewer same-address contention rounds than 1/thr).
// Blocks 0..63 zero out[g]'s 4 KB slab. Block 0 computes node_off.
// NOTE: never fuse with grid.sync() — R6 measured ~50 us per grid barrier
// (device-scope sync = cross-XCD L2 flush on MI355X).
// ---------------------------------------------------------------------------
__global__ __launch_bounds__(WG) void k_bucket(const int* __restrict__ edge,
                                               const int* __restrict__ batch,
                                               int2* __restrict__ bucket,
                                               int* __restrict__ cursor,
                                               int* __restrict__ node_off,
                                               float* __restrict__ out,
                                               int E, int N, int CAP) {
    __shared__ int lc[G64], lb[G64];
    int tid = threadIdx.x;
    int bid = blockIdx.x;
    if (tid < G64) lc[tid] = 0;

    if (bid < G64) {  // zero this graph's output slab (1024 floats)
        float4* o4 = (float4*)(out + ((size_t)bid << 10));
        o4[tid] = make_float4(0.f, 0.f, 0.f, 0.f);
    }
    __syncthreads();

    int base = bid * EPB + tid * EPT;
    int s[EPT], d[EPT], gg[EPT], rr[EPT];
    int nv = 0;   // valid count (EPT except in the tail block)
    if (base + EPT - 1 < E) {
        nv = EPT;
        if ((E & 3) == 0) {   // uniform branch: int4 fast path (aligned)
            int4 sv = *(const int4*)(edge + base);
            int4 dv = *(const int4*)(edge + E + base);
            s[0] = sv.x; s[1] = sv.y; s[2] = sv.z; s[3] = sv.w;
            d[0] = dv.x; d[1] = dv.y; d[2] = dv.z; d[3] = dv.w;
        } else {
#pragma unroll
            for (int j = 0; j < EPT; ++j) { s[j] = edge[base + j]; d[j] = edge[E + base + j]; }
        }
    } else if (base < E) {
        nv = E - base;
        for (int j = 0; j < nv; ++j) { s[j] = edge[base + j]; d[j] = edge[E + base + j]; }
    }
#pragma unroll
    for (int j = 0; j < EPT; ++j) {
        if (j < nv) {
            gg[j] = batch[s[j]];
            rr[j] = atomicAdd(&lc[gg[j]], 1);
        }
    }
    __syncthreads();
    if (tid < G64 && lc[tid]) lb[tid] = atomicAdd(&cursor[tid], lc[tid]);
    __syncthreads();
#pragma unroll
    for (int j = 0; j < EPT; ++j) {
        if (j < nv) {
            int pos = lb[gg[j]] + rr[j];
            if (pos < CAP) bucket[(size_t)gg[j] * CAP + pos] = make_int2(s[j], d[j]);
        }
    }

    if (bid == 0 && tid <= G64) {
        int lo = 0, hi = N;
        while (lo < hi) {
            int mid = (lo + hi) >> 1;
            if (batch[mid] < tid) lo = mid + 1; else hi = mid;
        }
        node_off[tid] = lo;
    }
}

// ---------------------------------------------------------------------------
// k_acc: block (g, split). INTEGER delta-histogram in LDS (proven R5).
// Per item 3 native ds_add_u32 deltas {q0, q1-q0, 2^20-q1} at
// clamp(ib..ib+2, 0, 33); telescopes exactly -> saturation exact.
// NEVER float LDS atomics (CAS loop, 7x serialization, R2).
// Edge loop 4x / node loop 2x unrolled with static indexing: all gather
// addresses issue before any dependent compute (loops are latency-bound at
// this occupancy, not throughput-bound).
// ---------------------------------------------------------------------------
__global__ __launch_bounds__(WG) void k_acc(const float* __restrict__ x,
                                            const float* __restrict__ v,
                                            const int2* __restrict__ bucket,
                                            const float* __restrict__ lin,
                                            const int* __restrict__ cursor,
                                            const int* __restrict__ node_off,
                                            float* __restrict__ out, int CAP) {
    __shared__ int   hist[34 * 32];   // [delta-slot 0..33][t]
    __shared__ float colf[32 * 32];   // prefixed float result
    int tid = threadIdx.x;
    for (int i = tid; i < 34 * 32; i += WG) hist[i] = 0;

    int g = blockIdx.x;
    int n0 = node_off[g], n1 = node_off[g + 1];
    int nn = n1 - n0;
    int ne = cursor[g]; if (ne > CAP) ne = CAP;
    int L = nn + ne;
    int ipc = (L + SPLITS - 1) / SPLITS;
    int lo = blockIdx.y * ipc;
    int hi = lo + ipc; if (hi > L) hi = L;

    int t = tid & 31, sub = tid >> 5;
    float v0 = v[t], v1 = v[32 + t], v2 = v[64 + t];

    float lin0 = lin[0];
    float dlin = lin[1] - lin[0];                 // > 0
    const float LOG2E = 1.4426950408889634f;
    float d2 = 200.f * dlin * LOG2E;              // exp-step in log2 units (~20.5)
    float inv_dlin = 1.f / dlin;
    float fstep = exp2f(-d2);                     // e-ratio per threshold (6.8e-7)
    __syncthreads();

    // deposit the 3 fixed-point deltas for height h with sign sg (+1 nodes,
    // -1 edges); forced-inline, static control flow
#define DEPOSIT(h, sg)                                                         \
    {                                                                          \
        float bs = ((h) - lin0) * inv_dlin;                                    \
        float bF = floorf(bs);                                                 \
        float e0 = exp2f((bs - bF) * d2);                                      \
        float s0 = __builtin_amdgcn_rcpf(1.f + e0);                            \
        float s1 = __builtin_amdgcn_rcpf(fmaf(e0, fstep, 1.f));                \
        int q0 = (int)(s0 * (float)SCALEI);                                    \
        int q1 = (int)(s1 * (float)SCALEI);                                    \
        int ib = (int)bF;                                                      \
        atomicAdd(&hist[min(33, max(0, ib)) * 32 + t], (sg) * q0);             \
        atomicAdd(&hist[min(33, max(0, ib + 1)) * 32 + t], (sg) * (q1 - q0));  \
        atomicAdd(&hist[min(33, max(0, ib + 2)) * 32 + t], (sg) * (SCALEI - q1)); \
    }

    // ---- node items (+): contiguous x rows, 2x unrolled ----
    int nhi = hi < nn ? hi : nn;
    {
        int idx = lo + sub;
        for (; idx + 8 < nhi; idx += 16) {
            const float* xa = x + (size_t)(n0 + idx) * 3;
            const float* xb = x + (size_t)(n0 + idx + 8) * 3;
            float xa0 = xa[0], xa1 = xa[1], xa2 = xa[2];
            float xb0 = xb[0], xb1 = xb[1], xb2 = xb[2];
            float hA = xa0 * v0 + xa1 * v1 + xa2 * v2;
            float hB = xb0 * v0 + xb1 * v1 + xb2 * v2;
            DEPOSIT(hA, 1)
            DEPOSIT(hB, 1)
        }
        for (; idx < nhi; idx += 8) {
            const float* xr = x + (size_t)(n0 + idx) * 3;
            float h = xr[0] * v0 + xr[1] * v1 + xr[2] * v2;
            DEPOSIT(h, 1)
        }
    }

    // ---- edge items (-): 4x unrolled, all gathers issued up front ----
    {
        const int2* bk = bucket + (size_t)g * CAP - nn;   // index by item idx
        int elo = lo > nn ? lo : nn;
        int idx = elo + sub;
        for (; idx + 24 < hi; idx += 32) {
            int2 sd[4];
#pragma unroll
            for (int u = 0; u < 4; ++u) sd[u] = bk[idx + 8 * u];
            float h[4];
#pragma unroll
            for (int u = 0; u < 4; ++u) {
                const float* xs = x + (size_t)sd[u].x * 3;
                const float* xd = x + (size_t)sd[u].y * 3;
                float hs = xs[0] * v0 + xs[1] * v1 + xs[2] * v2;
                float hd = xd[0] * v0 + xd[1] * v1 + xd[2] * v2;
                h[u] = fmaxf(hs, hd);
            }
#pragma unroll
            for (int u = 0; u < 4; ++u) DEPOSIT(h[u], -1)
        }
        for (; idx < hi; idx += 8) {
            int2 sd = bk[idx];
            const float* xs = x + (size_t)sd.x * 3;
            const float* xd = x + (size_t)sd.y * 3;
            float hs = xs[0] * v0 + xs[1] * v1 + xs[2] * v2;
            float hd = xd[0] * v0 + xd[1] * v1 + xd[2] * v2;
            float h = fmaxf(hs, hd);
            DEPOSIT(h, -1)
        }
    }
#undef DEPOSIT

    __syncthreads();
    // prefix over b per t-column (banks distinct across the 32 lanes), scale
    if (tid < 32) {
        int run = 0;
#pragma unroll
        for (int b = 0; b < 32; ++b) {
            run += hist[b * 32 + tid];
            colf[b * 32 + tid] = (float)run * ISCALE;
        }
    }
    __syncthreads();
    for (int c = tid; c < 1024; c += WG)
        unsafeAtomicAdd(&out[((size_t)g << 10) + c], colf[c]);
}

extern "C" void kernel_launch(void* const* d_in, const int* in_sizes, int n_in,
                              void* d_out, int out_size, void* d_ws, size_t ws_size,
                              hipStream_t stream) {
    const float* x     = (const float*)d_in[0];
    const float* v     = (const float*)d_in[1];
    const float* lin   = (const float*)d_in[2];
    const int*   edge  = (const int*)d_in[3];
    const int*   batch = (const int*)d_in[4];
    int N = in_sizes[4];
    int E = in_sizes[3] / 2;

    float* out = (float*)d_out;

    // workspace: [cursor 64][node_off 65][pad to 1024B][bucket G64*CAP*8B]
    int* cursor   = (int*)d_ws;
    int* node_off = cursor + G64;
    int2* bucket  = (int2*)((char*)d_ws + 1024);
    long long cap_ws = (long long)((ws_size - 1024) / ((size_t)G64 * sizeof(int2)));
    int CAP = (int)(cap_ws < (long long)E ? cap_ws : (long long)E);

    hipMemsetAsync(cursor, 0, G64 * sizeof(int), stream);

    k_bucket<<<(E + EPB - 1) / EPB, WG, 0, stream>>>(edge, batch, bucket, cursor,
                                                     node_off, out, E, N, CAP);
    dim3 grid(G64, SPLITS);
    k_acc<<<grid, WG, 0, stream>>>(x, v, bucket, lin, cursor, node_off, out, CAP);
}